// Round 1
// baseline (776.812 us; speedup 1.0000x reference)
//
#include <hip/hip_runtime.h>
#include <math.h>

#define N_NODES   100000
#define N_EDGES   3200000
#define N_GRAPHS  128
#define IN_DIM    128
#define HID       64
#define OUT_DIM   128

// ---------------- degree count ----------------
__global__ void k_count(const int* __restrict__ dst, int* __restrict__ cnt) {
    int i = blockIdx.x * 256 + threadIdx.x;
    if (i < N_EDGES) atomicAdd(&cnt[dst[i]], 1);
}

// ---------------- dinv = 1/sqrt(deg+1) ----------------
__global__ void k_dinv(const int* __restrict__ cnt, float* __restrict__ dinv) {
    int i = blockIdx.x * 256 + threadIdx.x;
    if (i < N_NODES) dinv[i] = 1.0f / sqrtf((float)cnt[i] + 1.0f);
}

// ---------------- prefix sum (3 stages) ----------------
__global__ void k_scan1(const int* __restrict__ cnt, int* __restrict__ partial,
                        int* __restrict__ blockSums) {
    __shared__ int s[256];
    int t = threadIdx.x, i = blockIdx.x * 256 + t;
    int v = (i < N_NODES) ? cnt[i] : 0;
    s[t] = v; __syncthreads();
    for (int d = 1; d < 256; d <<= 1) {
        int add = (t >= d) ? s[t - d] : 0;
        __syncthreads();
        s[t] += add;
        __syncthreads();
    }
    if (i < N_NODES) partial[i] = s[t] - v;   // exclusive within block
    if (t == 255) blockSums[blockIdx.x] = s[t];
}

__global__ void k_scan2(int* __restrict__ blockSums, int nb) {
    __shared__ int s[512];
    int t = threadIdx.x;
    int v = (t < nb) ? blockSums[t] : 0;
    s[t] = v; __syncthreads();
    for (int d = 1; d < 512; d <<= 1) {
        int add = (t >= d) ? s[t - d] : 0;
        __syncthreads();
        s[t] += add;
        __syncthreads();
    }
    if (t < nb) blockSums[t] = s[t] - v;      // exclusive
}

__global__ void k_scan3(int* __restrict__ row_ptr, const int* __restrict__ blockSums,
                        int* __restrict__ cursor) {
    int i = blockIdx.x * 256 + threadIdx.x;
    if (i < N_NODES) {
        int r = row_ptr[i] + blockSums[blockIdx.x];
        row_ptr[i] = r;
        cursor[i]  = r;
    }
    if (i == 0) row_ptr[N_NODES] = N_EDGES;
}

// ---------------- CSR placement ----------------
__global__ void k_place(const int* __restrict__ src, const int* __restrict__ dst,
                        int* __restrict__ cursor, int* __restrict__ csr_src) {
    int e = blockIdx.x * 256 + threadIdx.x;
    if (e < N_EDGES) {
        int p = atomicAdd(&cursor[dst[e]], 1);
        csr_src[p] = src[e];
    }
}

// ---------------- dense GEMM  Y[N,64] = X[N,K] @ W[K,64] ----------------
template <int K>
__global__ __launch_bounds__(256) void k_gemm(const float* __restrict__ X,
                                              const float* __restrict__ W,
                                              float* __restrict__ Y, int nrows) {
    __shared__ float Ws[K * 64];
    __shared__ float Xs[16][K];
    int t = threadIdx.x;
    for (int i = t; i < K * 64; i += 256) Ws[i] = W[i];
    int row0 = blockIdx.x * 16;
    for (int i = t; i < 16 * K; i += 256) {
        int r = i / K, k = i % K;
        int gr = row0 + r;
        Xs[r][k] = (gr < nrows) ? X[gr * K + k] : 0.0f;
    }
    __syncthreads();
    int c = t & 63, rg = t >> 6;
    float acc[4] = {0.f, 0.f, 0.f, 0.f};
#pragma unroll 4
    for (int k = 0; k < K; ++k) {
        float w = Ws[k * 64 + c];
#pragma unroll
        for (int i = 0; i < 4; ++i) acc[i] += Xs[rg * 4 + i][k] * w;
    }
#pragma unroll
    for (int i = 0; i < 4; ++i) {
        int gr = row0 + rg * 4 + i;
        if (gr < nrows) Y[gr * 64 + c] = acc[i];
    }
}

// ---------------- gather + self-loop + bias + relu ----------------
// one wave per node; 16 lanes x float4 cover 64 cols; 4 edges in flight
__global__ __launch_bounds__(256) void k_gather(const float* __restrict__ xw,
                                                const float* __restrict__ dinv,
                                                const int* __restrict__ row_ptr,
                                                const int* __restrict__ csr_src,
                                                const float* __restrict__ bias,
                                                float* __restrict__ hout) {
    int wave = threadIdx.x >> 6;
    int lane = threadIdx.x & 63;
    int n = blockIdx.x * 4 + wave;
    if (n >= N_NODES) return;
    int sub = lane >> 4, c4 = lane & 15;
    int start = row_ptr[n], end = row_ptr[n + 1];
    float ax = 0.f, ay = 0.f, az = 0.f, aw = 0.f;
    for (int i = start + sub; i < end; i += 4) {
        int s = csr_src[i];
        float w = dinv[s];
        const float4 v = *(const float4*)(xw + (size_t)s * 64 + c4 * 4);
        ax += w * v.x; ay += w * v.y; az += w * v.z; aw += w * v.w;
    }
    // reduce over the 4 edge-slots (lane^16, lane^32)
    ax += __shfl_xor(ax, 16, 64); ay += __shfl_xor(ay, 16, 64);
    az += __shfl_xor(az, 16, 64); aw += __shfl_xor(aw, 16, 64);
    ax += __shfl_xor(ax, 32, 64); ay += __shfl_xor(ay, 32, 64);
    az += __shfl_xor(az, 32, 64); aw += __shfl_xor(aw, 32, 64);
    if (sub == 0) {
        float dn = dinv[n];
        const float4 xn = *(const float4*)(xw + (size_t)n * 64 + c4 * 4);
        const float4 bv = *(const float4*)(bias + c4 * 4);
        float4 r;
        r.x = fmaxf(dn * (ax + dn * xn.x) + bv.x, 0.f);
        r.y = fmaxf(dn * (ay + dn * xn.y) + bv.y, 0.f);
        r.z = fmaxf(dn * (az + dn * xn.z) + bv.z, 0.f);
        r.w = fmaxf(dn * (aw + dn * xn.w) + bv.w, 0.f);
        *(float4*)(hout + (size_t)n * 64 + c4 * 4) = r;
    }
}

// ---------------- mean pool (batch is sorted) ----------------
__device__ __forceinline__ int lower_bound(const int* __restrict__ a, int n, int key) {
    int lo = 0, hi = n;
    while (lo < hi) {
        int mid = (lo + hi) >> 1;
        if (a[mid] < key) lo = mid + 1; else hi = mid;
    }
    return lo;
}

__global__ void k_pool(const float* __restrict__ h, const int* __restrict__ batch,
                       float* __restrict__ g) {
    int b = blockIdx.x;
    int t = threadIdx.x, c = t & 63, rg = t >> 6;
    __shared__ float s[4][64];
    int start = lower_bound(batch, N_NODES, b);
    int end   = lower_bound(batch, N_NODES, b + 1);
    float sum = 0.f;
    for (int n = start + rg; n < end; n += 4) sum += h[(size_t)n * 64 + c];
    s[rg][c] = sum;
    __syncthreads();
    if (rg == 0) {
        float tot = s[0][c] + s[1][c] + s[2][c] + s[3][c];
        float cntf = (float)(end - start);
        g[b * 64 + c] = tot / fmaxf(cntf, 1.0f);
    }
}

// ---------------- final linear  out[128,128] = g[128,64] @ Wl[64,128] + bl ----------------
__global__ void k_final(const float* __restrict__ g, const float* __restrict__ Wl,
                        const float* __restrict__ bl, float* __restrict__ out) {
    __shared__ float gs[64];
    int row = blockIdx.x, c = threadIdx.x;
    if (c < 64) gs[c] = g[row * 64 + c];
    __syncthreads();
    float acc = bl[c];
#pragma unroll
    for (int k = 0; k < 64; ++k) acc += gs[k] * Wl[k * 128 + c];
    out[row * 128 + c] = acc;
}

extern "C" void kernel_launch(void* const* d_in, const int* in_sizes, int n_in,
                              void* d_out, int out_size, void* d_ws, size_t ws_size,
                              hipStream_t stream) {
    const float* x    = (const float*)d_in[0];
    const int*   ei   = (const int*)d_in[1];
    const int*   batch= (const int*)d_in[2];
    const float* W1   = (const float*)d_in[3];
    const float* b1   = (const float*)d_in[4];
    const float* W2   = (const float*)d_in[5];
    const float* b2   = (const float*)d_in[6];
    const float* Wl   = (const float*)d_in[7];
    const float* bl   = (const float*)d_in[8];
    float* out = (float*)d_out;

    const int* src = ei;
    const int* dst = ei + N_EDGES;

    // workspace layout (all offsets 256B aligned)
    char* base = (char*)d_ws;
    int*   cnt     = (int*)  (base + 0);           // 400128
    float* dinv    = (float*)(base + 400128);      // 400128
    int*   row_ptr = (int*)  (base + 800256);      // 400128 (N+1 ints)
    int*   cursor  = (int*)  (base + 1200384);     // 400128
    int*   bsums   = (int*)  (base + 1600512);     // 2048
    int*   csr_src = (int*)  (base + 1602560);     // 12800000
    float* bufA    = (float*)(base + 14402560);    // 25600000
    float* bufB    = (float*)(base + 40002560);    // 25600000
    float* g       = (float*)(base + 65602560);    // 32768

    const int NB_SCAN = (N_NODES + 255) / 256;     // 391
    const int GB_E    = (N_EDGES + 255) / 256;     // 12500
    const int GB_N    = (N_NODES + 255) / 256;     // 391

    hipMemsetAsync(cnt, 0, N_NODES * sizeof(int), stream);
    k_count<<<GB_E, 256, 0, stream>>>(dst, cnt);
    k_dinv <<<GB_N, 256, 0, stream>>>(cnt, dinv);
    k_scan1<<<NB_SCAN, 256, 0, stream>>>(cnt, row_ptr, bsums);
    k_scan2<<<1, 512, 0, stream>>>(bsums, NB_SCAN);
    k_scan3<<<NB_SCAN, 256, 0, stream>>>(row_ptr, bsums, cursor);
    k_place<<<GB_E, 256, 0, stream>>>(src, dst, cursor, csr_src);

    // layer 1: xw1 = x @ W1 -> bufA ; h1 = gather(bufA) -> bufB
    k_gemm<IN_DIM><<<(N_NODES + 15) / 16, 256, 0, stream>>>(x, W1, bufA, N_NODES);
    k_gather<<<(N_NODES + 3) / 4, 256, 0, stream>>>(bufA, dinv, row_ptr, csr_src, b1, bufB);

    // layer 2: xw2 = h1 @ W2 -> bufA ; h2 = gather(bufA) -> bufB
    k_gemm<HID><<<(N_NODES + 15) / 16, 256, 0, stream>>>(bufB, W2, bufA, N_NODES);
    k_gather<<<(N_NODES + 3) / 4, 256, 0, stream>>>(bufA, dinv, row_ptr, csr_src, b2, bufB);

    // pool + final linear
    k_pool <<<N_GRAPHS, 256, 0, stream>>>(bufB, batch, g);
    k_final<<<N_GRAPHS, 128, 0, stream>>>(g, Wl, bl, out);
}